// Round 1
// baseline (1300.763 us; speedup 1.0000x reference)
//
#include <hip/hip_runtime.h>

#define B_    4
#define C_    256
#define C8_   32
#define T_    4096
#define NROW  320     // 32 q rows + 32 k rows + 256 v rows in the ws buffer
#define TQ    32      // query positions per attention block
#define STILE 256     // key/value tile length
#define SPAD  8       // LDS pad to break 8-way bank conflicts in reductions

// ---------------------------------------------------------------------------
// Projection: qkv[b][row][t] = W[row]·x[b][:][t] + bias[row]
// rows 0..31 = q (Wq), 32..63 = k (Wk), 64..319 = v (Wv)
// grid (T/1024, NROW/8, B), block 256, each thread does 4 t's (float4)
// ---------------------------------------------------------------------------
__global__ __launch_bounds__(256) void proj_kernel(
    const float* __restrict__ x,
    const float* __restrict__ Wq, const float* __restrict__ bq,
    const float* __restrict__ Wk, const float* __restrict__ bk,
    const float* __restrict__ Wv, const float* __restrict__ bv,
    float* __restrict__ qkv)
{
    const int b   = blockIdx.z;
    const int rg  = blockIdx.y;                    // row group of 8
    const int tid = threadIdx.x;
    const int t   = blockIdx.x * 1024 + tid * 4;

    __shared__ __align__(16) float ws[8][C_];
    __shared__ float bs[8];

    #pragma unroll
    for (int r = 0; r < 8; ++r) {
        int row = rg * 8 + r;
        const float* W; const float* bias; int ri;
        if (row < C8_)          { W = Wq; bias = bq; ri = row; }
        else if (row < 2 * C8_) { W = Wk; bias = bk; ri = row - C8_; }
        else                    { W = Wv; bias = bv; ri = row - 2 * C8_; }
        ws[r][tid] = W[ri * C_ + tid];
        if (tid == r) bs[r] = bias[ri];
    }
    __syncthreads();

    float4 acc[8];
    #pragma unroll
    for (int r = 0; r < 8; ++r) acc[r] = make_float4(0.f, 0.f, 0.f, 0.f);

    const float* xb = x + (size_t)b * C_ * T_ + t;
    for (int c = 0; c < C_; c += 4) {
        float4 xv0 = *(const float4*)(xb + (size_t)(c + 0) * T_);
        float4 xv1 = *(const float4*)(xb + (size_t)(c + 1) * T_);
        float4 xv2 = *(const float4*)(xb + (size_t)(c + 2) * T_);
        float4 xv3 = *(const float4*)(xb + (size_t)(c + 3) * T_);
        #pragma unroll
        for (int r = 0; r < 8; ++r) {
            const float4 w = *(const float4*)&ws[r][c];
            acc[r].x += w.x * xv0.x + w.y * xv1.x + w.z * xv2.x + w.w * xv3.x;
            acc[r].y += w.x * xv0.y + w.y * xv1.y + w.z * xv2.y + w.w * xv3.y;
            acc[r].z += w.x * xv0.z + w.y * xv1.z + w.z * xv2.z + w.w * xv3.z;
            acc[r].w += w.x * xv0.w + w.y * xv1.w + w.z * xv2.w + w.w * xv3.w;
        }
    }

    float* op = qkv + ((size_t)b * NROW + rg * 8) * T_ + t;
    #pragma unroll
    for (int r = 0; r < 8; ++r) {
        float4 o = acc[r];
        float bb = bs[r];
        o.x += bb; o.y += bb; o.z += bb; o.w += bb;
        *(float4*)(op + (size_t)r * T_) = o;
    }
}

// ---------------------------------------------------------------------------
// Flash-style attention + residual epilogue.
// One block = (batch b, TQ=32 consecutive query positions t0..t0+31).
// Loop over 16 s-tiles of 256 keys: pass A computes the 32x256 energy tile
// (thread = s), online-softmax stats via 8-lane shuffle groups; pass B
// accumulates o[c][tq] (thread = c) from float4 v loads and broadcast p reads.
// out = gamma * (o / l) + x
// ---------------------------------------------------------------------------
__global__ __launch_bounds__(256) void attn_kernel(
    const float* __restrict__ qkv,
    const float* __restrict__ x,
    const float* __restrict__ gamma,
    float* __restrict__ out)
{
    const int b   = blockIdx.y;
    const int t0  = blockIdx.x * TQ;
    const int tid = threadIdx.x;

    const float* qb = qkv + (size_t)b * NROW * T_;
    const float* kb = qb + (size_t)C8_ * T_;
    const float* vb = qb + (size_t)(2 * C8_) * T_;

    __shared__ __align__(16) float qs[C8_][TQ];          // 4 KB   [c][tq]
    __shared__ __align__(16) float ps[TQ][STILE + SPAD]; // ~33 KB [tq][s]
    __shared__ float mstat[TQ], lstat[TQ], alpha_s[TQ];

    // load q fragment: qs[c][tq] = q[b][c][t0+tq]
    for (int i = tid; i < C8_ * TQ; i += 256) {
        int c = i / TQ, tq = i % TQ;
        qs[c][tq] = qb[(size_t)c * T_ + t0 + tq];
    }
    if (tid < TQ) { mstat[tid] = -1e30f; lstat[tid] = 0.f; }

    float o[TQ];
    #pragma unroll
    for (int tq = 0; tq < TQ; ++tq) o[tq] = 0.f;

    __syncthreads();

    const int rtq  = tid >> 3;   // reduction row 0..31
    const int rlan = tid & 7;    // lane within 8-thread group

    for (int s0 = 0; s0 < T_; s0 += STILE) {
        // ---- pass A: energies for s = s0 + tid ----
        float e[TQ];
        #pragma unroll
        for (int tq = 0; tq < TQ; ++tq) e[tq] = 0.f;
        {
            const float* kp = kb + s0 + tid;
            for (int c = 0; c < C8_; ++c) {
                float kv = kp[(size_t)c * T_];
                #pragma unroll
                for (int tq = 0; tq < TQ; ++tq) e[tq] += qs[c][tq] * kv;
            }
        }
        __syncthreads();                     // previous tile's ps reads done
        #pragma unroll
        for (int tq = 0; tq < TQ; ++tq) ps[tq][tid] = e[tq];
        __syncthreads();

        // ---- tile max per tq (8 threads per row) ----
        {
            float pm = -1e30f;
            #pragma unroll
            for (int i = 0; i < STILE / 8; ++i)
                pm = fmaxf(pm, ps[rtq][rlan + 8 * i]);
            #pragma unroll
            for (int m = 4; m >= 1; m >>= 1)
                pm = fmaxf(pm, __shfl_xor(pm, m));
            if (rlan == 0) {
                float mold = mstat[rtq];
                float mnew = fmaxf(mold, pm);
                mstat[rtq]   = mnew;
                alpha_s[rtq] = __expf(mold - mnew);
            }
        }
        __syncthreads();

        // ---- p = exp(e - m); rescale accumulators ----
        #pragma unroll
        for (int tq = 0; tq < TQ; ++tq) {
            float p = __expf(e[tq] - mstat[tq]);
            ps[tq][tid] = p;
            o[tq] *= alpha_s[tq];
        }
        __syncthreads();

        // ---- tile sum per tq, update running l ----
        {
            float sm = 0.f;
            #pragma unroll
            for (int i = 0; i < STILE / 8; ++i)
                sm += ps[rtq][rlan + 8 * i];
            #pragma unroll
            for (int m = 4; m >= 1; m >>= 1)
                sm += __shfl_xor(sm, m);
            if (rlan == 0)
                lstat[rtq] = lstat[rtq] * alpha_s[rtq] + sm;
        }

        // ---- pass B: o[tq] += p[tq][s] * v[c][s]  (thread = c) ----
        {
            const float* vp = vb + (size_t)tid * T_ + s0;
            for (int s = 0; s < STILE; s += 4) {
                float4 vv = *(const float4*)(vp + s);
                #pragma unroll
                for (int tq = 0; tq < TQ; ++tq) {
                    float4 pp = *(const float4*)&ps[tq][s];
                    o[tq] += pp.x * vv.x + pp.y * vv.y + pp.z * vv.z + pp.w * vv.w;
                }
            }
        }
        // ps overwrite is fenced by the barrier at the top of next iteration
    }

    __syncthreads();
    const float g = gamma[0];
    const size_t base = ((size_t)b * C_ + tid) * T_ + t0;
    #pragma unroll
    for (int i = 0; i < TQ; i += 4) {
        float4 xv = *(const float4*)(x + base + i);
        float4 ov;
        ov.x = g * (o[i + 0] / lstat[i + 0]) + xv.x;
        ov.y = g * (o[i + 1] / lstat[i + 1]) + xv.y;
        ov.z = g * (o[i + 2] / lstat[i + 2]) + xv.z;
        ov.w = g * (o[i + 3] / lstat[i + 3]) + xv.w;
        *(float4*)(out + base + i) = ov;
    }
}

extern "C" void kernel_launch(void* const* d_in, const int* in_sizes, int n_in,
                              void* d_out, int out_size, void* d_ws, size_t ws_size,
                              hipStream_t stream) {
    const float* x     = (const float*)d_in[0];
    const float* Wq    = (const float*)d_in[1];
    const float* bq    = (const float*)d_in[2];
    const float* Wk    = (const float*)d_in[3];
    const float* bk    = (const float*)d_in[4];
    const float* Wv    = (const float*)d_in[5];
    const float* bv    = (const float*)d_in[6];
    const float* gamma = (const float*)d_in[7];
    float* out = (float*)d_out;
    float* qkv = (float*)d_ws;   // B*NROW*T floats = 20 MB

    dim3 pg(T_ / 1024, NROW / 8, B_);
    proj_kernel<<<pg, dim3(256), 0, stream>>>(x, Wq, bq, Wk, bk, Wv, bv, qkv);

    dim3 ag(T_ / TQ, B_);
    attn_kernel<<<ag, dim3(256), 0, stream>>>(qkv, x, gamma, out);
}

// Round 2
// 339.871 us; speedup vs baseline: 3.8272x; 3.8272x over previous
//
#include <hip/hip_runtime.h>

#define B_  4
#define C_  256
#define C8_ 32
#define T_  4096
#define TQ  32      // query rows per attention block
#define ST  64      // key/value tile length

typedef short v8s __attribute__((ext_vector_type(8)));   // 8 bf16 (4 VGPRs)
typedef float v4f __attribute__((ext_vector_type(4)));   // MFMA accum

static __device__ __forceinline__ unsigned short f2bf(float f) {
    union { float f; unsigned u; } c; c.f = f;
    unsigned r = c.u + 0x7fffu + ((c.u >> 16) & 1u);   // RNE
    return (unsigned short)(r >> 16);
}

// ---------------------------------------------------------------------------
// Projection. 16 rows x 1024 t per block. Outputs bf16:
//   qT[b][t][c8], kT[b][t][c8]  (transposed, so attn A/B frags are 16B loads)
//   vB[b][c][t]                 (natural, PV A-frags are 16B loads)
// ---------------------------------------------------------------------------
__global__ __launch_bounds__(256) void proj_kernel(
    const float* __restrict__ x,
    const float* __restrict__ Wq, const float* __restrict__ bq,
    const float* __restrict__ Wk, const float* __restrict__ bk,
    const float* __restrict__ Wv, const float* __restrict__ bv,
    unsigned short* __restrict__ qT, unsigned short* __restrict__ kT,
    unsigned short* __restrict__ vB)
{
    const int b   = blockIdx.z;
    const int rg  = blockIdx.y;                 // group of 16 rows
    const int tid = threadIdx.x;
    const int t   = blockIdx.x * 1024 + tid * 4;

    __shared__ __align__(16) float ws[16][C_];
    __shared__ float bs[16];

    #pragma unroll
    for (int r = 0; r < 16; ++r) {
        int row = rg * 16 + r;
        const float* W; const float* bias; int ri;
        if (row < C8_)          { W = Wq; bias = bq; ri = row; }
        else if (row < 2 * C8_) { W = Wk; bias = bk; ri = row - C8_; }
        else                    { W = Wv; bias = bv; ri = row - 2 * C8_; }
        ws[r][tid] = W[ri * C_ + tid];
        if (tid == r) bs[r] = bias[ri];
    }
    __syncthreads();

    float4 acc[16];
    #pragma unroll
    for (int r = 0; r < 16; ++r) acc[r] = make_float4(0.f, 0.f, 0.f, 0.f);

    const float* xb = x + (size_t)b * C_ * T_ + t;
    for (int c = 0; c < C_; c += 4) {
        float4 xv0 = *(const float4*)(xb + (size_t)(c + 0) * T_);
        float4 xv1 = *(const float4*)(xb + (size_t)(c + 1) * T_);
        float4 xv2 = *(const float4*)(xb + (size_t)(c + 2) * T_);
        float4 xv3 = *(const float4*)(xb + (size_t)(c + 3) * T_);
        #pragma unroll
        for (int r = 0; r < 16; ++r) {
            const float4 w = *(const float4*)&ws[r][c];   // wave-uniform broadcast
            acc[r].x += w.x * xv0.x + w.y * xv1.x + w.z * xv2.x + w.w * xv3.x;
            acc[r].y += w.x * xv0.y + w.y * xv1.y + w.z * xv2.y + w.w * xv3.y;
            acc[r].z += w.x * xv0.z + w.y * xv1.z + w.z * xv2.z + w.w * xv3.z;
            acc[r].w += w.x * xv0.w + w.y * xv1.w + w.z * xv2.w + w.w * xv3.w;
        }
    }

    const int row0 = rg * 16;
    if (row0 < 2 * C8_) {
        // q / k rows: transposed scatter stores (2 MB total across kernel, cheap)
        #pragma unroll
        for (int r = 0; r < 16; ++r) {
            int row = row0 + r;
            unsigned short* dst; int ri;
            if (row < C8_) { dst = qT; ri = row; } else { dst = kT; ri = row - C8_; }
            float bb = bs[r];
            unsigned short* p = dst + ((size_t)b * T_ + t) * C8_ + ri;
            p[0 * C8_] = f2bf(acc[r].x + bb);
            p[1 * C8_] = f2bf(acc[r].y + bb);
            p[2 * C8_] = f2bf(acc[r].z + bb);
            p[3 * C8_] = f2bf(acc[r].w + bb);
        }
    } else {
        #pragma unroll
        for (int r = 0; r < 16; ++r) {
            int ri = row0 - 2 * C8_ + r;
            float bb = bs[r];
            ushort4 o;
            o.x = f2bf(acc[r].x + bb);
            o.y = f2bf(acc[r].y + bb);
            o.z = f2bf(acc[r].z + bb);
            o.w = f2bf(acc[r].w + bb);
            *(ushort4*)(vB + ((size_t)b * C_ + ri) * T_ + t) = o;
        }
    }
}

// ---------------------------------------------------------------------------
// MFMA flash attention. Block = (b, 32 q rows), 4 waves, s-tiles of 64.
// Pass A: QK^T via mfma_f32_16x16x32_bf16 (K=32 = full channel dim), E tile
// to LDS (stride 67 -> ~2-way banks). Softmax: 8 threads/row, shuffles,
// online m/l; P -> bf16 LDS (stride 88, 16B aligned for b128 frag reads).
// Pass B: PV MFMA, wave w owns c in [64w, 64w+64). Epilogue: gamma*o/l + x.
// ---------------------------------------------------------------------------
__global__ __launch_bounds__(256) void attn_kernel(
    const unsigned short* __restrict__ qT,
    const unsigned short* __restrict__ kT,
    const unsigned short* __restrict__ vB,
    const float* __restrict__ x,
    const float* __restrict__ gamma,
    float* __restrict__ out)
{
    const int b    = blockIdx.y;
    const int t0   = blockIdx.x * TQ;
    const int tid  = threadIdx.x;
    const int wave = tid >> 6;
    const int lane = tid & 63;
    const int quad = lane >> 4;
    const int l16  = lane & 15;

    __shared__ float es[TQ][67];                          // 8576 B
    __shared__ __align__(16) unsigned short ps[TQ][88];   // 5632 B
    __shared__ float mstat[TQ], lstat[TQ], alpha_s[TQ];

    // persistent Q A-frags: A[m=t][k=c], lane holds qT[t0+ti*16+l16][quad*8+j]
    const unsigned short* qb = qT + ((size_t)b * T_ + t0) * C8_;
    v8s qfrag[2];
    #pragma unroll
    for (int ti = 0; ti < 2; ++ti)
        qfrag[ti] = *(const v8s*)(qb + (ti * 16 + l16) * C8_ + quad * 8);

    const unsigned short* kb = kT + (size_t)b * T_ * C8_;
    const unsigned short* vp = vB + ((size_t)b * C_ + wave * 64) * T_;

    v4f oacc[4][2];
    #pragma unroll
    for (int ci = 0; ci < 4; ++ci)
        #pragma unroll
        for (int ti = 0; ti < 2; ++ti)
            oacc[ci][ti] = (v4f){0.f, 0.f, 0.f, 0.f};

    if (tid < TQ) { mstat[tid] = -3.0e38f; lstat[tid] = 0.f; }
    __syncthreads();

    const int rtq  = tid >> 3;   // softmax row 0..31
    const int rlan = tid & 7;

    for (int s0 = 0; s0 < T_; s0 += ST) {
        // ---- pass A: wave w computes E[:, s0+16w .. +16) ----
        v8s kfrag = *(const v8s*)(kb + (size_t)(s0 + wave * 16 + l16) * C8_ + quad * 8);
        v4f z4 = (v4f){0.f, 0.f, 0.f, 0.f};
        v4f e0 = __builtin_amdgcn_mfma_f32_16x16x32_bf16(qfrag[0], kfrag, z4, 0, 0, 0);
        v4f e1 = __builtin_amdgcn_mfma_f32_16x16x32_bf16(qfrag[1], kfrag, z4, 0, 0, 0);
        const int scol = wave * 16 + l16;
        #pragma unroll
        for (int r = 0; r < 4; ++r) {
            es[quad * 4 + r][scol]      = e0[r];
            es[16 + quad * 4 + r][scol] = e1[r];
        }
        __syncthreads();

        // ---- softmax: 8 threads per row, 8 contiguous s each ----
        float ev[8];
        #pragma unroll
        for (int i = 0; i < 8; ++i) ev[i] = es[rtq][rlan * 8 + i];
        float pm = ev[0];
        #pragma unroll
        for (int i = 1; i < 8; ++i) pm = fmaxf(pm, ev[i]);
        #pragma unroll
        for (int m = 1; m <= 4; m <<= 1) pm = fmaxf(pm, __shfl_xor(pm, m));
        const float mold = mstat[rtq];
        const float mnew = fmaxf(mold, pm);
        float sum = 0.f;
        unsigned short pb[8];
        #pragma unroll
        for (int i = 0; i < 8; ++i) {
            float p = __expf(ev[i] - mnew);
            sum += p;
            pb[i] = f2bf(p);
        }
        {   // one 16B store of the 8 bf16 p's
            uint4 pk;
            pk.x = (unsigned)pb[0] | ((unsigned)pb[1] << 16);
            pk.y = (unsigned)pb[2] | ((unsigned)pb[3] << 16);
            pk.z = (unsigned)pb[4] | ((unsigned)pb[5] << 16);
            pk.w = (unsigned)pb[6] | ((unsigned)pb[7] << 16);
            *(uint4*)&ps[rtq][rlan * 8] = pk;
        }
        #pragma unroll
        for (int m = 1; m <= 4; m <<= 1) sum += __shfl_xor(sum, m);
        if (rlan == 0) {
            float al = __expf(mold - mnew);
            mstat[rtq]   = mnew;
            alpha_s[rtq] = al;
            lstat[rtq]   = lstat[rtq] * al + sum;
        }
        __syncthreads();

        // ---- rescale accumulators (alpha depends only on t = col = l16) ----
        const float al0 = alpha_s[l16];
        const float al1 = alpha_s[16 + l16];
        #pragma unroll
        for (int ci = 0; ci < 4; ++ci) {
            #pragma unroll
            for (int r = 0; r < 4; ++r) {
                oacc[ci][0][r] *= al0;
                oacc[ci][1][r] *= al1;
            }
        }

        // ---- pass B: PV MFMA, k = s in two chunks of 32 ----
        #pragma unroll
        for (int kc = 0; kc < 2; ++kc) {
            v8s pf0 = *(const v8s*)&ps[l16][kc * 32 + quad * 8];
            v8s pf1 = *(const v8s*)&ps[16 + l16][kc * 32 + quad * 8];
            #pragma unroll
            for (int ci = 0; ci < 4; ++ci) {
                v8s vf = *(const v8s*)(vp + (size_t)(ci * 16 + l16) * T_ + s0 + kc * 32 + quad * 8);
                oacc[ci][0] = __builtin_amdgcn_mfma_f32_16x16x32_bf16(vf, pf0, oacc[ci][0], 0, 0, 0);
                oacc[ci][1] = __builtin_amdgcn_mfma_f32_16x16x32_bf16(vf, pf1, oacc[ci][1], 0, 0, 0);
            }
        }
        // ps/es reuse next iter fenced by that iter's barriers
    }

    // ---- epilogue: out = gamma * (o / l) + x ----
    const float g   = gamma[0];
    const float il0 = 1.f / lstat[l16];
    const float il1 = 1.f / lstat[16 + l16];
    #pragma unroll
    for (int ci = 0; ci < 4; ++ci) {
        const int c = wave * 64 + ci * 16 + quad * 4;
        #pragma unroll
        for (int ti = 0; ti < 2; ++ti) {
            const float il = ti ? il1 : il0;
            const size_t idx = ((size_t)(b * C_ + c)) * T_ + t0 + ti * 16 + l16;
            #pragma unroll
            for (int r = 0; r < 4; ++r) {
                size_t a = idx + (size_t)r * T_;
                out[a] = g * oacc[ci][ti][r] * il + x[a];
            }
        }
    }
}

extern "C" void kernel_launch(void* const* d_in, const int* in_sizes, int n_in,
                              void* d_out, int out_size, void* d_ws, size_t ws_size,
                              hipStream_t stream) {
    const float* x     = (const float*)d_in[0];
    const float* Wq    = (const float*)d_in[1];
    const float* bq    = (const float*)d_in[2];
    const float* Wk    = (const float*)d_in[3];
    const float* bk    = (const float*)d_in[4];
    const float* Wv    = (const float*)d_in[5];
    const float* bv    = (const float*)d_in[6];
    const float* gamma = (const float*)d_in[7];
    float* out = (float*)d_out;

    unsigned short* qT = (unsigned short*)d_ws;           // [B][T][32] bf16, 1 MB
    unsigned short* kT = qT + (size_t)B_ * T_ * C8_;      // [B][T][32] bf16, 1 MB
    unsigned short* vB = kT + (size_t)B_ * T_ * C8_;      // [B][256][T] bf16, 8 MB

    dim3 pg(T_ / 1024, 320 / 16, B_);
    proj_kernel<<<pg, dim3(256), 0, stream>>>(x, Wq, bq, Wk, bk, Wv, bv, qT, kT, vB);

    dim3 ag(T_ / TQ, B_);
    attn_kernel<<<ag, dim3(256), 0, stream>>>(qT, kT, vB, x, gamma, out);
}

// Round 3
// 222.986 us; speedup vs baseline: 5.8334x; 1.5242x over previous
//
#include <hip/hip_runtime.h>

#define B_   4
#define C_   256
#define C8_  32
#define T_   4096
#define NROW 320
#define TQ   32      // query rows per attention block
#define ST   64      // key tile per iteration (16 per wave)

typedef short v8s __attribute__((ext_vector_type(8)));   // 8 bf16 (4 VGPRs)
typedef float v4f __attribute__((ext_vector_type(4)));   // MFMA accum

static __device__ __forceinline__ unsigned short f2bf(float f) {
    union { float f; unsigned u; } c; c.f = f;
    unsigned r = c.u + 0x7fffu + ((c.u >> 16) & 1u);   // RNE
    return (unsigned short)(r >> 16);
}

// ---------------------------------------------------------------------------
// Pack Wq|Wk|Wv -> Wb[320][256] bf16, biases -> bb[320] fp32.
// ---------------------------------------------------------------------------
__global__ __launch_bounds__(256) void convw_kernel(
    const float* __restrict__ Wq, const float* __restrict__ bq,
    const float* __restrict__ Wk, const float* __restrict__ bk,
    const float* __restrict__ Wv, const float* __restrict__ bv,
    unsigned short* __restrict__ Wb, float* __restrict__ bb)
{
    const int row = blockIdx.x * 16 + (threadIdx.x >> 4);
    const int c0  = (threadIdx.x & 15) * 16;
    const float* W; const float* bias; int ri;
    if (row < C8_)          { W = Wq; bias = bq; ri = row; }
    else if (row < 2 * C8_) { W = Wk; bias = bk; ri = row - C8_; }
    else                    { W = Wv; bias = bv; ri = row - 2 * C8_; }
    #pragma unroll
    for (int i = 0; i < 16; ++i)
        Wb[row * C_ + c0 + i] = f2bf(W[ri * C_ + c0 + i]);
    if (c0 == 0) bb[row] = bias[ri];
}

// ---------------------------------------------------------------------------
// Projection GEMM via MFMA. Block = (32 t, batch b), 4 waves.
// Stage x[:, t-tile] transposed to LDS as bf16 [t][c]; K-loop 8x32;
// wave w owns row-frags f = w+4j (f<2 -> q, f<4 -> k, else v).
// Outputs: qT/kT [b][t][32] bf16 (B-operand layout), vB [b][c][t] bf16.
// ---------------------------------------------------------------------------
__global__ __launch_bounds__(256) void proj_gemm(
    const float* __restrict__ x,
    const unsigned short* __restrict__ Wb, const float* __restrict__ bb,
    unsigned short* __restrict__ qT, unsigned short* __restrict__ kT,
    unsigned short* __restrict__ vB)
{
    const int b   = blockIdx.y;
    const int t0  = blockIdx.x * 32;
    const int tid = threadIdx.x;

    __shared__ __align__(16) unsigned short xtile[32][264];  // [t][c], pad 8

    // stage: coalesced float4 x reads, bf16 scalar transposed LDS writes
    #pragma unroll
    for (int it = 0; it < 8; ++it) {
        const int c  = it * 32 + (tid >> 3);
        const int t4 = (tid & 7) * 4;
        float4 xv = *(const float4*)(x + ((size_t)b * C_ + c) * T_ + t0 + t4);
        xtile[t4 + 0][c] = f2bf(xv.x);
        xtile[t4 + 1][c] = f2bf(xv.y);
        xtile[t4 + 2][c] = f2bf(xv.z);
        xtile[t4 + 3][c] = f2bf(xv.w);
    }
    __syncthreads();

    const int wave = tid >> 6;
    const int lane = tid & 63;
    const int quad = lane >> 4;
    const int l16  = lane & 15;

    v4f acc[5][2];
    #pragma unroll
    for (int j = 0; j < 5; ++j)
        #pragma unroll
        for (int ti = 0; ti < 2; ++ti) acc[j][ti] = (v4f){0.f, 0.f, 0.f, 0.f};

    for (int kc = 0; kc < 8; ++kc) {
        v8s bf[2];
        #pragma unroll
        for (int ti = 0; ti < 2; ++ti)
            bf[ti] = *(const v8s*)&xtile[ti * 16 + l16][kc * 32 + quad * 8];
        #pragma unroll
        for (int j = 0; j < 5; ++j) {
            const int row = (wave + 4 * j) * 16 + l16;
            v8s af = *(const v8s*)(Wb + row * C_ + kc * 32 + quad * 8);
            acc[j][0] = __builtin_amdgcn_mfma_f32_16x16x32_bf16(af, bf[0], acc[j][0], 0, 0, 0);
            acc[j][1] = __builtin_amdgcn_mfma_f32_16x16x32_bf16(af, bf[1], acc[j][1], 0, 0, 0);
        }
    }

    // epilogue: D row = proj row (16f+quad*4+r), col = t (l16)
    #pragma unroll
    for (int j = 0; j < 5; ++j) {
        const int f    = wave + 4 * j;
        const int rowb = f * 16;
        float4 bias4 = *(const float4*)(bb + rowb + quad * 4);
        #pragma unroll
        for (int ti = 0; ti < 2; ++ti) {
            const int t = t0 + ti * 16 + l16;
            unsigned short p0 = f2bf(acc[j][ti][0] + bias4.x);
            unsigned short p1 = f2bf(acc[j][ti][1] + bias4.y);
            unsigned short p2 = f2bf(acc[j][ti][2] + bias4.z);
            unsigned short p3 = f2bf(acc[j][ti][3] + bias4.w);
            if (f < 2) {
                ushort4 pk = make_ushort4(p0, p1, p2, p3);
                *(ushort4*)(qT + ((size_t)b * T_ + t) * C8_ + rowb + quad * 4) = pk;
            } else if (f < 4) {
                ushort4 pk = make_ushort4(p0, p1, p2, p3);
                *(ushort4*)(kT + ((size_t)b * T_ + t) * C8_ + (rowb - 32) + quad * 4) = pk;
            } else {
                const int c = rowb - 64 + quad * 4;
                vB[((size_t)b * C_ + c + 0) * T_ + t] = p0;
                vB[((size_t)b * C_ + c + 1) * T_ + t] = p1;
                vB[((size_t)b * C_ + c + 2) * T_ + t] = p2;
                vB[((size_t)b * C_ + c + 3) * T_ + t] = p3;
            }
        }
    }
}

// ---------------------------------------------------------------------------
// MFMA flash attention, register softmax. Block = (b, 32 q), 4 waves.
// Pass A: E = mfma(A=K, B=Q) -> lane holds 4 s-rows at col t=l16 -> per-t
// reduce in regs (2 shuffles) + one b128 LDS partial. exp in regs; m/l
// replicated per lane. P -> psT[t][s] bf16 (stride 72, double-buffered).
// Pass B: O = mfma(A=V, B=psT). k/v prefetched under pass-B MFMA.
// ---------------------------------------------------------------------------
__global__ __launch_bounds__(256) void attn_kernel(
    const unsigned short* __restrict__ qT,
    const unsigned short* __restrict__ kT,
    const unsigned short* __restrict__ vB,
    const float* __restrict__ x,
    const float* __restrict__ gamma,
    float* __restrict__ out)
{
    const int b    = blockIdx.y;
    const int t0   = blockIdx.x * TQ;
    const int tid  = threadIdx.x;
    const int wave = tid >> 6;
    const int lane = tid & 63;
    const int quad = lane >> 4;
    const int l16  = lane & 15;

    __shared__ __align__(16) unsigned short psT[2][TQ][72];   // 9216 B
    __shared__ __align__(16) float pstat[2][2][TQ][4];        // [buf][max|sum][t][wave]

    // persistent Q B-frags: B[k=c][n=t], lane holds qT[t0+ti*16+l16][quad*8+j]
    const unsigned short* qb = qT + ((size_t)b * T_ + t0) * C8_;
    v8s qfrag[2];
    #pragma unroll
    for (int ti = 0; ti < 2; ++ti)
        qfrag[ti] = *(const v8s*)(qb + (ti * 16 + l16) * C8_ + quad * 8);

    const unsigned short* kb = kT + (size_t)b * T_ * C8_;
    const unsigned short* vb = vB + ((size_t)b * C_ + wave * 64) * T_;

    v4f oacc[4][2];
    #pragma unroll
    for (int ci = 0; ci < 4; ++ci)
        #pragma unroll
        for (int ti = 0; ti < 2; ++ti) oacc[ci][ti] = (v4f){0.f, 0.f, 0.f, 0.f};

    float m_run[2] = {-3.0e38f, -3.0e38f};
    float l_run[2] = {0.f, 0.f};

    // prefetch tile 0
    v8s kf = *(const v8s*)(kb + (size_t)(wave * 16 + l16) * C8_ + quad * 8);
    v8s vf[4][2];
    #pragma unroll
    for (int ci = 0; ci < 4; ++ci)
        #pragma unroll
        for (int kc = 0; kc < 2; ++kc)
            vf[ci][kc] = *(const v8s*)(vb + (size_t)(ci * 16 + l16) * T_ + kc * 32 + quad * 8);

    const v4f z4 = (v4f){0.f, 0.f, 0.f, 0.f};

    for (int it = 0; it < T_ / ST; ++it) {
        const int buf = it & 1;
        const int s0n = ((it + 1) & (T_ / ST - 1)) * ST;   // wraps to 0 on tail

        // ---- pass A: E[s][t] for this wave's 16 s ----
        v4f e0 = __builtin_amdgcn_mfma_f32_16x16x32_bf16(kf, qfrag[0], z4, 0, 0, 0);
        v4f e1 = __builtin_amdgcn_mfma_f32_16x16x32_bf16(kf, qfrag[1], z4, 0, 0, 0);

        // per-t max over this wave's 16 s (4 regs + quad shuffles)
        float wm0 = fmaxf(fmaxf(e0[0], e0[1]), fmaxf(e0[2], e0[3]));
        float wm1 = fmaxf(fmaxf(e1[0], e1[1]), fmaxf(e1[2], e1[3]));
        wm0 = fmaxf(wm0, __shfl_xor(wm0, 16)); wm0 = fmaxf(wm0, __shfl_xor(wm0, 32));
        wm1 = fmaxf(wm1, __shfl_xor(wm1, 16)); wm1 = fmaxf(wm1, __shfl_xor(wm1, 32));
        if (quad == 0) {
            pstat[buf][0][l16][wave]      = wm0;
            pstat[buf][0][16 + l16][wave] = wm1;
        }
        __syncthreads();   // barrier 1 (also drains this tile's prefetched k/v)

        float mnew[2], alpha[2];
        #pragma unroll
        for (int ti = 0; ti < 2; ++ti) {
            v4f gm = *(const v4f*)&pstat[buf][0][ti * 16 + l16][0];
            float g = fmaxf(fmaxf(gm[0], gm[1]), fmaxf(gm[2], gm[3]));
            mnew[ti]  = fmaxf(m_run[ti], g);
            alpha[ti] = __expf(m_run[ti] - mnew[ti]);
            m_run[ti] = mnew[ti];
        }

        // p = exp(e - m) in registers; wave-partial sums; pack to psT
        float p0[4], p1[4];
        float ws0 = 0.f, ws1 = 0.f;
        #pragma unroll
        for (int r = 0; r < 4; ++r) {
            p0[r] = __expf(e0[r] - mnew[0]); ws0 += p0[r];
            p1[r] = __expf(e1[r] - mnew[1]); ws1 += p1[r];
        }
        ws0 += __shfl_xor(ws0, 16); ws0 += __shfl_xor(ws0, 32);
        ws1 += __shfl_xor(ws1, 16); ws1 += __shfl_xor(ws1, 32);
        if (quad == 0) {
            pstat[buf][1][l16][wave]      = ws0;
            pstat[buf][1][16 + l16][wave] = ws1;
        }
        {
            const int scol = wave * 16 + quad * 4;
            ushort4 a = make_ushort4(f2bf(p0[0]), f2bf(p0[1]), f2bf(p0[2]), f2bf(p0[3]));
            ushort4 c = make_ushort4(f2bf(p1[0]), f2bf(p1[1]), f2bf(p1[2]), f2bf(p1[3]));
            *(ushort4*)&psT[buf][l16][scol]      = a;
            *(ushort4*)&psT[buf][16 + l16][scol] = c;
        }
        __syncthreads();   // barrier 2

        // finalize l, rescale o
        #pragma unroll
        for (int ti = 0; ti < 2; ++ti) {
            v4f gs = *(const v4f*)&pstat[buf][1][ti * 16 + l16][0];
            float s = (gs[0] + gs[1]) + (gs[2] + gs[3]);
            l_run[ti] = l_run[ti] * alpha[ti] + s;
        }
        #pragma unroll
        for (int ci = 0; ci < 4; ++ci)
            #pragma unroll
            for (int r = 0; r < 4; ++r) {
                oacc[ci][0][r] *= alpha[0];
                oacc[ci][1][r] *= alpha[1];
            }

        // prefetch next tile's k/v (flies under pass-B MFMA)
        kf = *(const v8s*)(kb + (size_t)(s0n + wave * 16 + l16) * C8_ + quad * 8);
        v8s vn[4][2];
        #pragma unroll
        for (int ci = 0; ci < 4; ++ci)
            #pragma unroll
            for (int kc = 0; kc < 2; ++kc)
                vn[ci][kc] = *(const v8s*)(vb + (size_t)(ci * 16 + l16) * T_ + s0n + kc * 32 + quad * 8);

        // ---- pass B: O += V * P ----
        #pragma unroll
        for (int kc = 0; kc < 2; ++kc) {
            v8s bf0 = *(const v8s*)&psT[buf][l16][kc * 32 + quad * 8];
            v8s bf1 = *(const v8s*)&psT[buf][16 + l16][kc * 32 + quad * 8];
            #pragma unroll
            for (int ci = 0; ci < 4; ++ci) {
                oacc[ci][0] = __builtin_amdgcn_mfma_f32_16x16x32_bf16(vf[ci][kc], bf0, oacc[ci][0], 0, 0, 0);
                oacc[ci][1] = __builtin_amdgcn_mfma_f32_16x16x32_bf16(vf[ci][kc], bf1, oacc[ci][1], 0, 0, 0);
            }
        }
        #pragma unroll
        for (int ci = 0; ci < 4; ++ci)
            #pragma unroll
            for (int kc = 0; kc < 2; ++kc) vf[ci][kc] = vn[ci][kc];
    }

    // ---- epilogue: out = gamma * (o / l) + x ----
    const float g   = gamma[0];
    const float il0 = 1.f / l_run[0];
    const float il1 = 1.f / l_run[1];
    #pragma unroll
    for (int ci = 0; ci < 4; ++ci) {
        const int c = wave * 64 + ci * 16 + quad * 4;
        #pragma unroll
        for (int ti = 0; ti < 2; ++ti) {
            const float il = ti ? il1 : il0;
            const size_t idx = ((size_t)(b * C_ + c)) * T_ + t0 + ti * 16 + l16;
            #pragma unroll
            for (int r = 0; r < 4; ++r) {
                size_t a = idx + (size_t)r * T_;
                out[a] = g * oacc[ci][ti][r] * il + x[a];
            }
        }
    }
}

extern "C" void kernel_launch(void* const* d_in, const int* in_sizes, int n_in,
                              void* d_out, int out_size, void* d_ws, size_t ws_size,
                              hipStream_t stream) {
    const float* x     = (const float*)d_in[0];
    const float* Wq    = (const float*)d_in[1];
    const float* bq    = (const float*)d_in[2];
    const float* Wk    = (const float*)d_in[3];
    const float* bk    = (const float*)d_in[4];
    const float* Wv    = (const float*)d_in[5];
    const float* bv    = (const float*)d_in[6];
    const float* gamma = (const float*)d_in[7];
    float* out = (float*)d_out;

    unsigned short* qT = (unsigned short*)d_ws;            // [B][T][32] bf16, 1 MB
    unsigned short* kT = qT + (size_t)B_ * T_ * C8_;       // [B][T][32] bf16, 1 MB
    unsigned short* vB = kT + (size_t)B_ * T_ * C8_;       // [B][256][T] bf16, 8 MB
    unsigned short* Wb = vB + (size_t)B_ * C_ * T_;        // [320][256] bf16
    float*          bb = (float*)(Wb + (size_t)NROW * C_); // [320] fp32

    convw_kernel<<<dim3(NROW / 16), dim3(256), 0, stream>>>(Wq, bq, Wk, bk, Wv, bv, Wb, bb);
    proj_gemm<<<dim3(T_ / 32, B_), dim3(256), 0, stream>>>(x, Wb, bb, qT, kT, vB);
    attn_kernel<<<dim3(T_ / TQ, B_), dim3(256), 0, stream>>>(qT, kT, vB, x, gamma, out);
}

// Round 4
// 151.076 us; speedup vs baseline: 8.6100x; 1.4760x over previous
//
#include <hip/hip_runtime.h>
#include <hip/hip_bf16.h>

#define B_    4
#define C_    256
#define C8_   32
#define T_    4096
#define NROW  320
#define TQ    32      // query rows per attention block
#define ST    128     // key tile per softmax round (32 per wave)
#define SPLIT 2
#define SH    (T_ / SPLIT)

typedef short v8s __attribute__((ext_vector_type(8)));   // 8 bf16 (4 VGPRs)
typedef float v4f __attribute__((ext_vector_type(4)));   // MFMA accum

static __device__ __forceinline__ unsigned short f2bf(float f) {
    union { float f; unsigned u; } c; c.f = f;
    unsigned r = c.u + 0x7fffu + ((c.u >> 16) & 1u);   // RNE
    return (unsigned short)(r >> 16);
}
static __device__ __forceinline__ float bf2f(unsigned short s) {
    union { unsigned u; float f; } c; c.u = (unsigned)s << 16;
    return c.f;
}
static __device__ __forceinline__ uint2 pk4bf(float a, float b, float c, float d) {
    __hip_bfloat162 lo = __float22bfloat162_rn(make_float2(a, b));
    __hip_bfloat162 hi = __float22bfloat162_rn(make_float2(c, d));
    union { __hip_bfloat162 h; unsigned u; } U0, U1;
    U0.h = lo; U1.h = hi;
    return make_uint2(U0.u, U1.u);
}

// ---------------------------------------------------------------------------
// Pack Wq|Wk|Wv -> Wb[320][256] bf16, biases -> bb[320] fp32.
// ---------------------------------------------------------------------------
__global__ __launch_bounds__(256) void convw_kernel(
    const float* __restrict__ Wq, const float* __restrict__ bq,
    const float* __restrict__ Wk, const float* __restrict__ bk,
    const float* __restrict__ Wv, const float* __restrict__ bv,
    unsigned short* __restrict__ Wb, float* __restrict__ bb)
{
    const int row = blockIdx.x * 16 + (threadIdx.x >> 4);
    const int c0  = (threadIdx.x & 15) * 16;
    const float* W; const float* bias; int ri;
    if (row < C8_)          { W = Wq; bias = bq; ri = row; }
    else if (row < 2 * C8_) { W = Wk; bias = bk; ri = row - C8_; }
    else                    { W = Wv; bias = bv; ri = row - 2 * C8_; }
    #pragma unroll
    for (int i = 0; i < 16; ++i)
        Wb[row * C_ + c0 + i] = f2bf(W[ri * C_ + c0 + i]);
    if (c0 == 0) bb[row] = bias[ri];
}

// ---------------------------------------------------------------------------
// Projection GEMM via MFMA. Block = (32 t, batch b), 4 waves.
// Wb A-frag loads pipelined across the K-loop; V epilogue goes through an
// LDS transpose for coalesced ushort8 global stores.
// ---------------------------------------------------------------------------
__global__ __launch_bounds__(256) void proj_gemm(
    const float* __restrict__ x,
    const unsigned short* __restrict__ Wb, const float* __restrict__ bb,
    unsigned short* __restrict__ qT, unsigned short* __restrict__ kT,
    unsigned short* __restrict__ vB)
{
    const int b   = blockIdx.y;
    const int t0  = blockIdx.x * 32;
    const int tid = threadIdx.x;

    __shared__ __align__(16) unsigned short xtile[32][264];  // [t][c]
    __shared__ __align__(16) unsigned short vtile[256][40];  // [c][t], 80B rows

    const int wave = tid >> 6;
    const int lane = tid & 63;
    const int quad = lane >> 4;
    const int l16  = lane & 15;

    // prefetch kc=0 A-frags (independent of LDS)
    v8s af[5];
    #pragma unroll
    for (int j = 0; j < 5; ++j)
        af[j] = *(const v8s*)(Wb + ((wave + 4 * j) * 16 + l16) * C_ + quad * 8);

    // stage x tile: coalesced float4 reads, bf16 transposed LDS writes
    #pragma unroll
    for (int it = 0; it < 8; ++it) {
        const int c  = it * 32 + (tid >> 3);
        const int t4 = (tid & 7) * 4;
        float4 xv = *(const float4*)(x + ((size_t)b * C_ + c) * T_ + t0 + t4);
        xtile[t4 + 0][c] = f2bf(xv.x);
        xtile[t4 + 1][c] = f2bf(xv.y);
        xtile[t4 + 2][c] = f2bf(xv.z);
        xtile[t4 + 3][c] = f2bf(xv.w);
    }
    __syncthreads();

    v4f acc[5][2];
    #pragma unroll
    for (int j = 0; j < 5; ++j)
        #pragma unroll
        for (int ti = 0; ti < 2; ++ti) acc[j][ti] = (v4f){0.f, 0.f, 0.f, 0.f};

    for (int kc = 0; kc < 8; ++kc) {
        v8s bf[2];
        #pragma unroll
        for (int ti = 0; ti < 2; ++ti)
            bf[ti] = *(const v8s*)&xtile[ti * 16 + l16][kc * 32 + quad * 8];
        v8s afn[5];
        if (kc < 7) {
            #pragma unroll
            for (int j = 0; j < 5; ++j)
                afn[j] = *(const v8s*)(Wb + ((wave + 4 * j) * 16 + l16) * C_ + (kc + 1) * 32 + quad * 8);
        }
        #pragma unroll
        for (int j = 0; j < 5; ++j) {
            acc[j][0] = __builtin_amdgcn_mfma_f32_16x16x32_bf16(af[j], bf[0], acc[j][0], 0, 0, 0);
            acc[j][1] = __builtin_amdgcn_mfma_f32_16x16x32_bf16(af[j], bf[1], acc[j][1], 0, 0, 0);
        }
        #pragma unroll
        for (int j = 0; j < 5; ++j) af[j] = afn[j];
    }

    // epilogue. j==0: f = wave in 0..3 -> q/k direct stores; j>=1: v via LDS.
    {
        const int f    = wave;                 // j = 0
        const int rowb = f * 16;
        float4 bias4 = *(const float4*)(bb + rowb + quad * 4);
        #pragma unroll
        for (int ti = 0; ti < 2; ++ti) {
            const int t = t0 + ti * 16 + l16;
            ushort4 pk = make_ushort4(f2bf(acc[0][ti][0] + bias4.x),
                                      f2bf(acc[0][ti][1] + bias4.y),
                                      f2bf(acc[0][ti][2] + bias4.z),
                                      f2bf(acc[0][ti][3] + bias4.w));
            if (f < 2)
                *(ushort4*)(qT + ((size_t)b * T_ + t) * C8_ + rowb + quad * 4) = pk;
            else
                *(ushort4*)(kT + ((size_t)b * T_ + t) * C8_ + (rowb - 32) + quad * 4) = pk;
        }
    }
    #pragma unroll
    for (int j = 1; j < 5; ++j) {
        const int cbase = (wave + 4 * (j - 1)) * 16 + quad * 4;
        float4 bias4 = *(const float4*)(bb + 64 + cbase);
        #pragma unroll
        for (int ti = 0; ti < 2; ++ti) {
            const int t = ti * 16 + l16;
            vtile[cbase + 0][t] = f2bf(acc[j][ti][0] + bias4.x);
            vtile[cbase + 1][t] = f2bf(acc[j][ti][1] + bias4.y);
            vtile[cbase + 2][t] = f2bf(acc[j][ti][2] + bias4.z);
            vtile[cbase + 3][t] = f2bf(acc[j][ti][3] + bias4.w);
        }
    }
    __syncthreads();
    #pragma unroll
    for (int rep = 0; rep < 4; ++rep) {
        const int idx = rep * 256 + tid;
        const int c   = idx >> 2;
        const int tch = idx & 3;
        v8s v = *(const v8s*)&vtile[c][tch * 8];
        *(v8s*)(vB + ((size_t)b * C_ + c) * T_ + t0 + tch * 8) = v;
    }
}

// ---------------------------------------------------------------------------
// MFMA flash attention, ST=128 rounds, s-split x2, partials to ws.
// Flat grid 1024: bid&7 -> (batch, s-half) [XCD L2 locality], bid>>3 -> t tile.
// ---------------------------------------------------------------------------
__global__ __launch_bounds__(256, 3) void attn_kernel(
    const unsigned short* __restrict__ qT,
    const unsigned short* __restrict__ kT,
    const unsigned short* __restrict__ vB,
    unsigned short* __restrict__ opart,
    float* __restrict__ mpart, float* __restrict__ lpart)
{
    const int bid  = blockIdx.x;
    const int xg   = bid & 7;
    const int b    = xg >> 1;
    const int sh   = xg & 1;
    const int t0   = (bid >> 3) * TQ;
    const int sbase = sh * SH;
    const int tid  = threadIdx.x;
    const int wave = tid >> 6;
    const int lane = tid & 63;
    const int quad = lane >> 4;
    const int l16  = lane & 15;

    __shared__ __align__(16) unsigned short psT[2][TQ][136];  // [t][s], 17.4 KB
    __shared__ __align__(16) float pstat[2][2][TQ][4];        // [buf][max|sum][t][wave]

    const unsigned short* qb = qT + ((size_t)b * T_ + t0) * C8_;
    v8s qfrag[2];
    #pragma unroll
    for (int tf = 0; tf < 2; ++tf)
        qfrag[tf] = *(const v8s*)(qb + (tf * 16 + l16) * C8_ + quad * 8);

    const unsigned short* kb = kT + (size_t)b * T_ * C8_;
    const unsigned short* vb = vB + ((size_t)b * C_ + wave * 64) * T_;

    v4f oacc[4][2];
    #pragma unroll
    for (int ci = 0; ci < 4; ++ci)
        #pragma unroll
        for (int tf = 0; tf < 2; ++tf) oacc[ci][tf] = (v4f){0.f, 0.f, 0.f, 0.f};

    float m_run[2] = {-3.0e38f, -3.0e38f};
    float l_run[2] = {0.f, 0.f};

    // round-0 K frags
    v8s kf[2];
    #pragma unroll
    for (int k = 0; k < 2; ++k)
        kf[k] = *(const v8s*)(kb + (size_t)(sbase + wave * 32 + k * 16 + l16) * C8_ + quad * 8);

    const v4f z4 = (v4f){0.f, 0.f, 0.f, 0.f};

    for (int it = 0; it < SH / ST; ++it) {
        const int buf = it & 1;
        const int s0  = sbase + it * ST;
        const int s0n = sbase + ((it + 1) & (SH / ST - 1)) * ST;

        // current round V kc01 (latency hides under pass A + softmax)
        v8s vf01[4][2];
        #pragma unroll
        for (int ci = 0; ci < 4; ++ci)
            #pragma unroll
            for (int kc = 0; kc < 2; ++kc)
                vf01[ci][kc] = *(const v8s*)(vb + (size_t)(ci * 16 + l16) * T_ + s0 + kc * 32 + quad * 8);

        // ---- pass A: E[s][t], wave owns 32 s ----
        v4f e[2][2];
        #pragma unroll
        for (int k = 0; k < 2; ++k)
            #pragma unroll
            for (int tf = 0; tf < 2; ++tf)
                e[k][tf] = __builtin_amdgcn_mfma_f32_16x16x32_bf16(kf[k], qfrag[tf], z4, 0, 0, 0);

        // local per-t max over 8 regs + quad shuffles
        #pragma unroll
        for (int tf = 0; tf < 2; ++tf) {
            float wm = fmaxf(fmaxf(fmaxf(e[0][tf][0], e[0][tf][1]), fmaxf(e[0][tf][2], e[0][tf][3])),
                             fmaxf(fmaxf(e[1][tf][0], e[1][tf][1]), fmaxf(e[1][tf][2], e[1][tf][3])));
            wm = fmaxf(wm, __shfl_xor(wm, 16));
            wm = fmaxf(wm, __shfl_xor(wm, 32));
            if (quad == 0) pstat[buf][0][tf * 16 + l16][wave] = wm;
        }
        __syncthreads();   // B1

        float mnew[2], alpha[2];
        #pragma unroll
        for (int tf = 0; tf < 2; ++tf) {
            v4f gm = *(const v4f*)&pstat[buf][0][tf * 16 + l16][0];
            float g = fmaxf(fmaxf(gm[0], gm[1]), fmaxf(gm[2], gm[3]));
            mnew[tf]  = fmaxf(m_run[tf], g);
            alpha[tf] = __expf(m_run[tf] - mnew[tf]);
            m_run[tf] = mnew[tf];
        }

        float wsum[2] = {0.f, 0.f};
        #pragma unroll
        for (int k = 0; k < 2; ++k)
            #pragma unroll
            for (int tf = 0; tf < 2; ++tf) {
                float p0 = __expf(e[k][tf][0] - mnew[tf]);
                float p1 = __expf(e[k][tf][1] - mnew[tf]);
                float p2 = __expf(e[k][tf][2] - mnew[tf]);
                float p3 = __expf(e[k][tf][3] - mnew[tf]);
                wsum[tf] += (p0 + p1) + (p2 + p3);
                uint2 pk = pk4bf(p0, p1, p2, p3);
                *(uint2*)&psT[buf][tf * 16 + l16][wave * 32 + k * 16 + quad * 4] = pk;
            }
        #pragma unroll
        for (int tf = 0; tf < 2; ++tf) {
            float s = wsum[tf];
            s += __shfl_xor(s, 16);
            s += __shfl_xor(s, 32);
            if (quad == 0) pstat[buf][1][tf * 16 + l16][wave] = s;
        }
        __syncthreads();   // B2

        #pragma unroll
        for (int tf = 0; tf < 2; ++tf) {
            v4f gs = *(const v4f*)&pstat[buf][1][tf * 16 + l16][0];
            l_run[tf] = l_run[tf] * alpha[tf] + ((gs[0] + gs[1]) + (gs[2] + gs[3]));
        }
        if (__any(alpha[0] != 1.f || alpha[1] != 1.f)) {
            #pragma unroll
            for (int ci = 0; ci < 4; ++ci)
                #pragma unroll
                for (int r = 0; r < 4; ++r) {
                    oacc[ci][0][r] *= alpha[0];
                    oacc[ci][1][r] *= alpha[1];
                }
        }

        // V kc23 + next-round K frags
        v8s vf23[4][2];
        #pragma unroll
        for (int ci = 0; ci < 4; ++ci)
            #pragma unroll
            for (int kc = 0; kc < 2; ++kc)
                vf23[ci][kc] = *(const v8s*)(vb + (size_t)(ci * 16 + l16) * T_ + s0 + (kc + 2) * 32 + quad * 8);
        v8s kfn[2];
        #pragma unroll
        for (int k = 0; k < 2; ++k)
            kfn[k] = *(const v8s*)(kb + (size_t)(s0n + wave * 32 + k * 16 + l16) * C8_ + quad * 8);

        // ---- pass B: O += V * P over 4 k-chunks ----
        #pragma unroll
        for (int kc = 0; kc < 4; ++kc) {
            v8s pb0 = *(const v8s*)&psT[buf][l16][kc * 32 + quad * 8];
            v8s pb1 = *(const v8s*)&psT[buf][16 + l16][kc * 32 + quad * 8];
            #pragma unroll
            for (int ci = 0; ci < 4; ++ci) {
                v8s vfx = (kc < 2) ? vf01[ci][kc] : vf23[ci][kc - 2];
                oacc[ci][0] = __builtin_amdgcn_mfma_f32_16x16x32_bf16(vfx, pb0, oacc[ci][0], 0, 0, 0);
                oacc[ci][1] = __builtin_amdgcn_mfma_f32_16x16x32_bf16(vfx, pb1, oacc[ci][1], 0, 0, 0);
            }
        }
        kf[0] = kfn[0]; kf[1] = kfn[1];
    }

    // ---- store partials: raw o (bf16), m, l ----
    #pragma unroll
    for (int ci = 0; ci < 4; ++ci) {
        const int c = wave * 64 + ci * 16 + quad * 4;
        #pragma unroll
        for (int tf = 0; tf < 2; ++tf) {
            const size_t idx = ((size_t)((sh * B_ + b) * C_) + c) * T_ + t0 + tf * 16 + l16;
            #pragma unroll
            for (int r = 0; r < 4; ++r)
                opart[idx + (size_t)r * T_] = f2bf(oacc[ci][tf][r]);
        }
    }
    if (wave == 0 && quad == 0) {
        #pragma unroll
        for (int tf = 0; tf < 2; ++tf) {
            const int t = t0 + tf * 16 + l16;
            mpart[(size_t)(sh * B_ + b) * T_ + t] = m_run[tf];
            lpart[(size_t)(sh * B_ + b) * T_ + t] = l_run[tf];
        }
    }
}

// ---------------------------------------------------------------------------
// Combine s-split partials + gamma/residual epilogue.
// ---------------------------------------------------------------------------
__global__ __launch_bounds__(256) void combine_kernel(
    const unsigned short* __restrict__ opart,
    const float* __restrict__ mpart, const float* __restrict__ lpart,
    const float* __restrict__ x, const float* __restrict__ gamma,
    float* __restrict__ out)
{
    const int t  = blockIdx.x * 256 + threadIdx.x;
    const int b  = blockIdx.y;
    const int c0 = blockIdx.z * 64;
    const float g = gamma[0];

    const float m0 = mpart[(size_t)b * T_ + t];
    const float m1 = mpart[(size_t)(B_ + b) * T_ + t];
    const float l0 = lpart[(size_t)b * T_ + t];
    const float l1 = lpart[(size_t)(B_ + b) * T_ + t];
    const float m  = fmaxf(m0, m1);
    const float w0 = __expf(m0 - m), w1 = __expf(m1 - m);
    const float inv = 1.f / (l0 * w0 + l1 * w1);
    const float gw0 = g * w0 * inv, gw1 = g * w1 * inv;

    const size_t o0b = ((size_t)(b * C_ + c0)) * T_ + t;
    const size_t o1b = ((size_t)((B_ + b) * C_ + c0)) * T_ + t;
    #pragma unroll 4
    for (int i = 0; i < 64; ++i) {
        float o0 = bf2f(opart[o0b + (size_t)i * T_]);
        float o1 = bf2f(opart[o1b + (size_t)i * T_]);
        size_t ix = ((size_t)(b * C_ + c0 + i)) * T_ + t;
        out[ix] = gw0 * o0 + gw1 * o1 + x[ix];
    }
}

extern "C" void kernel_launch(void* const* d_in, const int* in_sizes, int n_in,
                              void* d_out, int out_size, void* d_ws, size_t ws_size,
                              hipStream_t stream) {
    const float* x     = (const float*)d_in[0];
    const float* Wq    = (const float*)d_in[1];
    const float* bq    = (const float*)d_in[2];
    const float* Wk    = (const float*)d_in[3];
    const float* bk    = (const float*)d_in[4];
    const float* Wv    = (const float*)d_in[5];
    const float* bv    = (const float*)d_in[6];
    const float* gamma = (const float*)d_in[7];
    float* out = (float*)d_out;

    unsigned short* qT = (unsigned short*)d_ws;              // 1 MB
    unsigned short* kT = qT + (size_t)B_ * T_ * C8_;         // 1 MB
    unsigned short* vB = kT + (size_t)B_ * T_ * C8_;         // 8 MB
    unsigned short* Wb = vB + (size_t)B_ * C_ * T_;          // 160 KB
    unsigned short* opart = Wb + (size_t)NROW * C_;          // 16 MB [split][B][C][T] bf16
    float* bb    = (float*)(opart + (size_t)SPLIT * B_ * C_ * T_);  // 1.25 KB
    float* mpart = bb + NROW;                                // [split][B][T]
    float* lpart = mpart + (size_t)SPLIT * B_ * T_;          // [split][B][T]

    convw_kernel<<<dim3(NROW / 16), dim3(256), 0, stream>>>(Wq, bq, Wk, bk, Wv, bv, Wb, bb);
    proj_gemm<<<dim3(T_ / 32, B_), dim3(256), 0, stream>>>(x, Wb, bb, qT, kT, vB);
    attn_kernel<<<dim3(T_ / TQ * SPLIT * B_ / 8 * 8 / 8), dim3(256), 0, stream>>>(qT, kT, vB, opart, mpart, lpart);
    combine_kernel<<<dim3(T_ / 256, B_, C_ / 64), dim3(256), 0, stream>>>(opart, mpart, lpart, x, gamma, out);
}